// Round 3
// baseline (14218.951 us; speedup 1.0000x reference)
//
#include <hip/hip_runtime.h>
#include <hip/hip_fp16.h>

typedef _Float16 f16;
typedef _Float16 f16x4 __attribute__((ext_vector_type(4)));
typedef _Float16 f16x8 __attribute__((ext_vector_type(8)));
typedef float f32x16 __attribute__((ext_vector_type(16)));

#define NN 8000
#define O2OFF 160000   /* T*N */
#define XOFF  320000   /* 2*T*N */

// ---------- A fp32 -> fp16 (once per launch; 256MB read / 128MB write) ----------
__global__ void k_cvt_a(const float* __restrict__ A, f16* __restrict__ A16) {
  long idx = (long)blockIdx.x * blockDim.x + threadIdx.x;
  long stride = (long)gridDim.x * blockDim.x;
  const long total = (long)NN * NN / 4;
  const float4* A4 = (const float4*)A;
  f16x4* O4 = (f16x4*)A16;
  for (long i = idx; i < total; i += stride) {
    float4 v = A4[i];
    f16x4 o = { (f16)v.x, (f16)v.y, (f16)v.z, (f16)v.w };
    O4[i] = o;
  }
}

// ---------- WtT16[c][m] = fp16(Wt[m][c]);  x0 = y1 - y2 ----------
__global__ void k_setup(const float* __restrict__ Wt, f16* __restrict__ WtT16,
                        const float* __restrict__ y1, const float* __restrict__ y2,
                        float* __restrict__ x0out) {
  int idx = blockIdx.x * blockDim.x + threadIdx.x;
  int stride = gridDim.x * blockDim.x;
  for (int i = idx; i < 128 * 128; i += stride) {
    int c = i >> 7, m = i & 127;
    WtT16[i] = (f16)Wt[m * 128 + c];
  }
  for (int i = idx; i < NN * 16; i += stride) {
    x0out[i] = y1[i] - y2[i];
  }
}

// ---------- embedding: sT[c][n] (transposed state, f32) ----------
__global__ __launch_bounds__(256) void k_embed(
    const float* __restrict__ y1, const float* __restrict__ y2,
    const float* __restrict__ Wi1a, const float* __restrict__ bi1a,
    const float* __restrict__ Wi1b, const float* __restrict__ bi1b,
    const float* __restrict__ Wi2a, const float* __restrict__ bi2a,
    const float* __restrict__ Wi2b, const float* __restrict__ bi2b,
    float* __restrict__ sT) {
  __shared__ float g[2][64][65];          // +1 pad: conflict-free column reads
  int n0 = blockIdx.x * 64;
  int tid = threadIdx.x;
  int n = tid & 63, q = tid >> 6;          // q = wave id (uniform per wave)

  float ya[16], yb[16];
  #pragma unroll
  for (int i = 0; i < 16; i++) { ya[i] = y1[(n0 + n) * 16 + i]; yb[i] = y2[(n0 + n) * 16 + i]; }
  #pragma unroll
  for (int j = 0; j < 16; j++) {
    int h = q * 16 + j;
    float a1 = bi1a[h], a2 = bi2a[h];
    #pragma unroll
    for (int i = 0; i < 16; i++) { a1 += ya[i] * Wi1a[i * 64 + h]; a2 += yb[i] * Wi2a[i * 64 + h]; }
    g[0][n][h] = tanhf(a1);
    g[1][n][h] = tanhf(a2);
  }
  __syncthreads();
  // c-strip per wave: c = q*32 + j2
  for (int j2 = 0; j2 < 32; j2++) {
    int c = q * 32 + j2;
    int ch = c >> 6, cc = c & 63;
    const float* W = ch ? Wi2b : Wi1b;
    float acc = ch ? bi2b[cc] : bi1b[cc];
    #pragma unroll 8
    for (int h = 0; h < 64; h++) acc += g[ch][n][h] * W[h * 64 + cc];
    sT[(long)c * NN + n0 + n] = acc;
  }
}

// ---------- uT16 = fp16(Wt^T @ sT)  (initial input to eval 0) ----------
__global__ __launch_bounds__(256) void k_wtmul(const float* __restrict__ sT,
                                               const f16* __restrict__ WtT16,
                                               f16* __restrict__ uT) {
  __shared__ __attribute__((aligned(16))) char ulds[32 * 128 * 2]; // [i 32][m 128] f16, XOR swz
  int n0 = blockIdx.x * 32;
  int tid = threadIdx.x;
  int n = tid & 31, mg = tid >> 5;        // 8 m-groups of 16
  for (int j = 0; j < 16; j += 2) {
    int m = mg * 16 + j;
    f16 v0 = (f16)sT[(long)m * NN + n0 + n];
    f16 v1 = (f16)sT[(long)(m + 1) * NN + n0 + n];
    int byte = n * 256 + ((m * 2) ^ ((n & 15) << 4));
    f16 pk[2] = { v0, v1 };
    *(unsigned int*)(ulds + byte) = *(unsigned int*)pk;
  }
  __syncthreads();
  int w = tid >> 6, l = tid & 63, lr = l & 31, lg = l >> 5;
  f32x16 acc = {};
  #pragma unroll
  for (int s = 0; s < 8; s++) {
    int m0 = s * 16 + 8 * lg;
    f16x8 af = *(const f16x8*)(WtT16 + (32 * w + lr) * 128 + m0);
    int byte = lr * 256 + ((m0 * 2) ^ ((lr & 15) << 4));
    f16x8 bf = *(const f16x8*)(ulds + byte);
    acc = __builtin_amdgcn_mfma_f32_32x32x16_f16(af, bf, acc, 0, 0, 0);
  }
  #pragma unroll
  for (int r = 0; r < 16; r++) {
    int c = 32 * w + (r & 3) + 8 * (r >> 2) + 4 * lg;
    uT[(long)c * NN + n0 + lr] = (f16)acc[r];
  }
}

// ---------- heads at t = 0 ----------
__global__ void k_heads0(const float* __restrict__ sT,
                         const float* __restrict__ Wo1, const float* __restrict__ bo1,
                         const float* __restrict__ Wo2, const float* __restrict__ bo2,
                         float* __restrict__ out) {
  int n = blockIdx.x * blockDim.x + threadIdx.x;
  if (n >= NN) return;
  float p1 = bo1[0], p2 = bo2[0];
  #pragma unroll 8
  for (int c = 0; c < 64; c++) {
    p1 += sT[(long)c * NN + n] * Wo1[c];
    p2 += sT[(long)(64 + c) * NN + n] * Wo2[c];
  }
  out[n] = 1.f / (1.f + expf(-p1));
  out[O2OFF + n] = 1.f / (1.f + expf(-p2));
}

// ---------- fused ODE eval: k = relu(uT@A^T + bt); RK4 combine; uT_next = Wt^T t_next ----------
__global__ __launch_bounds__(256) void k_feval(
    const f16* __restrict__ A16, const f16* __restrict__ uin,
    const f16* __restrict__ WtT16, const float* __restrict__ bt,
    const float* __restrict__ vt, int st, int variant,
    float* __restrict__ sT, float* __restrict__ accT,
    f16* __restrict__ uout,
    const float* __restrict__ Wo1, const float* __restrict__ bo1,
    const float* __restrict__ Wo2, const float* __restrict__ bo2,
    float* __restrict__ out) {
  __shared__ __attribute__((aligned(16))) char ulds[32 * 128 * 2];
  __shared__ float hbuf[2][32];

  int i0 = blockIdx.x * 32;
  int tid = threadIdx.x;
  int w = tid >> 6, l = tid & 63, lr = l & 31, lg = l >> 5;

  // ---- main GEMM: D[c][i] = sum_k uT[c][k] * A[i][k] ----
  // Dual accumulators + 32-wide K step break the serial same-acc MFMA chain;
  // unroll 4 keeps ~16KB/wave of loads in flight (Little's law: ~12KB/CU
  // needed to saturate the L2 stream at 1 wave/SIMD).
  // a-side (uT rows): zero intra-block reuse -> nontemporal, keeps L1 for the
  // b-side A16 rows which ARE reused 4x across the block's waves.
  const f16* aptr = uin + (long)(32 * w + lr) * NN + 8 * lg;   // Aop row c, k-contig
  const f16* bptr = A16 + (long)(i0 + lr) * NN + 8 * lg;       // Bop col i (= A row), k-contig
  f32x16 acc0 = {}, acc1 = {};
  #pragma unroll 4
  for (int k = 0; k < NN; k += 32) {
    f16x8 a0 = __builtin_nontemporal_load((const f16x8*)aptr);
    f16x8 b0 = *(const f16x8*)bptr;
    f16x8 a1 = __builtin_nontemporal_load((const f16x8*)(aptr + 16));
    f16x8 b1 = *(const f16x8*)(bptr + 16);
    aptr += 32; bptr += 32;
    acc0 = __builtin_amdgcn_mfma_f32_32x32x16_f16(a0, b0, acc0, 0, 0, 0);
    acc1 = __builtin_amdgcn_mfma_f32_32x32x16_f16(a1, b1, acc1, 0, 0, 0);
  }
  f32x16 acc = acc0 + acc1;

  float dt = vt[st + 1] - vt[st];
  int i = i0 + lr;

  // ---- relu + bias, RK4 combine (elementwise, block-local) ----
  float tn[16];
  #pragma unroll
  for (int r = 0; r < 16; r++) {
    int c = 32 * w + (r & 3) + 8 * (r >> 2) + 4 * lg;
    float kv = acc[r] + bt[c];
    kv = kv > 0.f ? kv : 0.f;
    long g = (long)c * NN + i;
    if (variant == 0) {
      accT[g] = kv;
      tn[r] = sT[g] + 0.5f * dt * kv;
    } else if (variant == 1) {
      accT[g] += 2.f * kv;
      tn[r] = sT[g] + 0.5f * dt * kv;
    } else if (variant == 2) {
      accT[g] += 2.f * kv;
      tn[r] = sT[g] + dt * kv;
    } else {
      float sn = sT[g] + (dt / 6.f) * (accT[g] + kv);
      sT[g] = sn;
      tn[r] = sn;
    }
  }

  // ---- stage t_next (fp16) into LDS [i][m], XOR-swizzled (4 row bits) ----
  #pragma unroll
  for (int r = 0; r < 16; r += 2) {
    int c = 32 * w + (r & 3) + 8 * (r >> 2) + 4 * lg;   // r even -> c even, pair contiguous
    f16 pk[2] = { (f16)tn[r], (f16)tn[r + 1] };
    int byte = lr * 256 + ((c * 2) ^ ((lr & 15) << 4));
    *(unsigned int*)(ulds + byte) = *(unsigned int*)pk;
  }
  __syncthreads();

  // ---- uT_next tile = Wt^T @ t_next  (K = 128) ----
  f32x16 uacc = {};
  #pragma unroll
  for (int s = 0; s < 8; s++) {
    int m0 = s * 16 + 8 * lg;
    f16x8 af = *(const f16x8*)(WtT16 + (32 * w + lr) * 128 + m0);
    int byte = lr * 256 + ((m0 * 2) ^ ((lr & 15) << 4));
    f16x8 bf = *(const f16x8*)(ulds + byte);
    uacc = __builtin_amdgcn_mfma_f32_32x32x16_f16(af, bf, uacc, 0, 0, 0);
  }
  #pragma unroll
  for (int r = 0; r < 16; r++) {
    int c = 32 * w + (r & 3) + 8 * (r >> 2) + 4 * lg;
    uout[(long)c * NN + i] = (f16)uacc[r];
  }

  // ---- heads (variant 3 only): sigmoid(s_new[:,:64]@Wo1), sigmoid(s_new[:,64:]@Wo2) ----
  if (variant == 3) {
    if (tid < 64) ((float*)hbuf)[tid] = 0.f;
    __syncthreads();
    float p1 = 0.f, p2 = 0.f;
    #pragma unroll
    for (int r = 0; r < 16; r++) {
      int c = 32 * w + (r & 3) + 8 * (r >> 2) + 4 * lg;
      if (c < 64) p1 += tn[r] * Wo1[c];
      else        p2 += tn[r] * Wo2[c - 64];
    }
    atomicAdd(&hbuf[0][lr], p1);
    atomicAdd(&hbuf[1][lr], p2);
    __syncthreads();
    if (tid < 32) {
      float z = hbuf[0][tid] + bo1[0];
      out[(st + 1) * NN + i0 + tid] = 1.f / (1.f + expf(-z));
    } else if (tid < 64) {
      float z = hbuf[1][tid - 32] + bo2[0];
      out[O2OFF + (st + 1) * NN + i0 + (tid - 32)] = 1.f / (1.f + expf(-z));
    }
  }
}

extern "C" void kernel_launch(void* const* d_in, const int* in_sizes, int n_in,
                              void* d_out, int out_size, void* d_ws, size_t ws_size,
                              hipStream_t stream) {
  const float* vt   = (const float*)d_in[0];
  const float* y1   = (const float*)d_in[1];
  const float* y2   = (const float*)d_in[2];
  const float* A    = (const float*)d_in[3];
  const float* Wi1a = (const float*)d_in[4];
  const float* bi1a = (const float*)d_in[5];
  const float* Wi1b = (const float*)d_in[6];
  const float* bi1b = (const float*)d_in[7];
  const float* Wi2a = (const float*)d_in[8];
  const float* bi2a = (const float*)d_in[9];
  const float* Wi2b = (const float*)d_in[10];
  const float* bi2b = (const float*)d_in[11];
  const float* Wt   = (const float*)d_in[12];
  const float* bt   = (const float*)d_in[13];
  const float* Wo1  = (const float*)d_in[14];
  const float* bo1  = (const float*)d_in[15];
  const float* Wo2  = (const float*)d_in[16];
  const float* bo2  = (const float*)d_in[17];
  float* out = (float*)d_out;

  char* ws = (char*)d_ws;
  f16*   A16   = (f16*)(ws);                      // 128,000,000 B
  f16*   WtT16 = (f16*)(ws + 128000000);          //      32,768 B
  f16*   uA    = (f16*)(ws + 128032768);          //   2,048,000 B
  f16*   uB    = (f16*)(ws + 130080768);          //   2,048,000 B
  float* sT    = (float*)(ws + 132128768);        //   4,096,000 B
  float* accT  = (float*)(ws + 136224768);        //   4,096,000 B  (total ~140.3 MB)

  k_cvt_a <<<2048, 256, 0, stream>>>(A, A16);
  k_setup <<<512, 256, 0, stream>>>(Wt, WtT16, y1, y2, out + XOFF);
  k_embed <<<125, 256, 0, stream>>>(y1, y2, Wi1a, bi1a, Wi1b, bi1b,
                                    Wi2a, bi2a, Wi2b, bi2b, sT);
  k_wtmul <<<250, 256, 0, stream>>>(sT, WtT16, uA);
  k_heads0<<<32, 256, 0, stream>>>(sT, Wo1, bo1, Wo2, bo2, out);

  f16* bufs[2] = { uA, uB };
  int pp = 0;
  for (int st = 0; st < 19; st++) {
    for (int v = 0; v < 4; v++) {
      k_feval<<<250, 256, 0, stream>>>(A16, bufs[pp], WtT16, bt, vt, st, v,
                                       sT, accT, bufs[pp ^ 1],
                                       Wo1, bo1, Wo2, bo2, out);
      pp ^= 1;
    }
  }
}

// Round 7
// 6990.025 us; speedup vs baseline: 2.0342x; 2.0342x over previous
//
#include <hip/hip_runtime.h>
#include <hip/hip_fp16.h>

typedef _Float16 f16;
typedef _Float16 f16x8 __attribute__((ext_vector_type(8)));
typedef float f32x16 __attribute__((ext_vector_type(16)));

#define NN 8000
#define O2OFF 160000   /* T*N */
#define XOFF  320000   /* 2*T*N */

// ---------- A fp32 -> fp16 in MFMA-fragment-packed order ----------
// A16p[((tile*500 + s)*64 + l)*8 + j] = A[32*tile + (l&31)][16*s + 8*(l>>5) + j]
// so k_feval's b-fragment load is ONE contiguous 1KB burst per wave per k-step.
__global__ __launch_bounds__(256) void k_cvt_a(const float* __restrict__ A,
                                               f16* __restrict__ A16p) {
  long g = (long)blockIdx.x * 256 + threadIdx.x;   // one (tile,s,l) per thread
  int l = (int)(g & 63);
  long rest = g >> 6;
  int s = (int)(rest % 500);
  int tile = (int)(rest / 500);
  int row = tile * 32 + (l & 31);
  int col = s * 16 + (l >> 5) * 8;
  const float4* src = (const float4*)(A + (long)row * NN + col);
  float4 v0 = src[0], v1 = src[1];
  f16x8 o = { (f16)v0.x, (f16)v0.y, (f16)v0.z, (f16)v0.w,
              (f16)v1.x, (f16)v1.y, (f16)v1.z, (f16)v1.w };
  *(f16x8*)(A16p + g * 8) = o;
}

// ---------- WtT16[c][m] = fp16(Wt[m][c]);  x0 = y1 - y2 ----------
__global__ void k_setup(const float* __restrict__ Wt, f16* __restrict__ WtT16,
                        const float* __restrict__ y1, const float* __restrict__ y2,
                        float* __restrict__ x0out) {
  int idx = blockIdx.x * blockDim.x + threadIdx.x;
  int stride = gridDim.x * blockDim.x;
  for (int i = idx; i < 128 * 128; i += stride) {
    int c = i >> 7, m = i & 127;
    WtT16[i] = (f16)Wt[m * 128 + c];
  }
  for (int i = idx; i < NN * 16; i += stride) {
    x0out[i] = y1[i] - y2[i];
  }
}

// ---------- embedding: sT[c][n] (transposed state, f32) ----------
__global__ __launch_bounds__(256) void k_embed(
    const float* __restrict__ y1, const float* __restrict__ y2,
    const float* __restrict__ Wi1a, const float* __restrict__ bi1a,
    const float* __restrict__ Wi1b, const float* __restrict__ bi1b,
    const float* __restrict__ Wi2a, const float* __restrict__ bi2a,
    const float* __restrict__ Wi2b, const float* __restrict__ bi2b,
    float* __restrict__ sT) {
  __shared__ float g[2][64][65];          // +1 pad: conflict-free column reads
  int n0 = blockIdx.x * 64;
  int tid = threadIdx.x;
  int n = tid & 63, q = tid >> 6;          // q = wave id (uniform per wave)

  float ya[16], yb[16];
  #pragma unroll
  for (int i = 0; i < 16; i++) { ya[i] = y1[(n0 + n) * 16 + i]; yb[i] = y2[(n0 + n) * 16 + i]; }
  #pragma unroll
  for (int j = 0; j < 16; j++) {
    int h = q * 16 + j;
    float a1 = bi1a[h], a2 = bi2a[h];
    #pragma unroll
    for (int i = 0; i < 16; i++) { a1 += ya[i] * Wi1a[i * 64 + h]; a2 += yb[i] * Wi2a[i * 64 + h]; }
    g[0][n][h] = tanhf(a1);
    g[1][n][h] = tanhf(a2);
  }
  __syncthreads();
  for (int j2 = 0; j2 < 32; j2++) {
    int c = q * 32 + j2;
    int ch = c >> 6, cc = c & 63;
    const float* W = ch ? Wi2b : Wi1b;
    float acc = ch ? bi2b[cc] : bi1b[cc];
    #pragma unroll 8
    for (int h = 0; h < 64; h++) acc += g[ch][n][h] * W[h * 64 + cc];
    sT[(long)c * NN + n0 + n] = acc;
  }
}

// ---------- uT16 = fp16(Wt^T @ sT), written FRAGMENT-PACKED ----------
__global__ __launch_bounds__(256) void k_wtmul(const float* __restrict__ sT,
                                               const f16* __restrict__ WtT16,
                                               f16* __restrict__ uT) {
  __shared__ __attribute__((aligned(16))) char ulds[32 * 128 * 2]; // [i 32][m 128] f16, XOR swz
  int n0 = blockIdx.x * 32;
  int tid = threadIdx.x;
  int n = tid & 31, mg = tid >> 5;        // 8 m-groups of 16
  for (int j = 0; j < 16; j += 2) {
    int m = mg * 16 + j;
    f16 v0 = (f16)sT[(long)m * NN + n0 + n];
    f16 v1 = (f16)sT[(long)(m + 1) * NN + n0 + n];
    int byte = n * 256 + ((m * 2) ^ ((n & 15) << 4));
    f16 pk[2] = { v0, v1 };
    *(unsigned int*)(ulds + byte) = *(unsigned int*)pk;
  }
  __syncthreads();
  int w = tid >> 6, l = tid & 63, lr = l & 31, lg = l >> 5;
  f32x16 acc = {};
  #pragma unroll
  for (int s = 0; s < 8; s++) {
    int m0 = s * 16 + 8 * lg;
    f16x8 af = *(const f16x8*)(WtT16 + (32 * w + lr) * 128 + m0);
    int byte = lr * 256 + ((m0 * 2) ^ ((lr & 15) << 4));
    f16x8 bf = *(const f16x8*)(ulds + byte);
    acc = __builtin_amdgcn_mfma_f32_32x32x16_f16(af, bf, acc, 0, 0, 0);
  }
  // packed write: u[c=32w+cc][k=n0+lr] -> up[((w*500+s)*64+lp)*8 + j]
  #pragma unroll
  for (int r = 0; r < 16; r++) {
    int cc = (r & 3) + 8 * (r >> 2) + 4 * lg;
    int s  = (n0 + lr) >> 4;
    int lp = cc + 32 * ((lr >> 3) & 1);
    int j  = lr & 7;
    uT[((long)(w * 500 + s) * 64 + lp) * 8 + j] = (f16)acc[r];
  }
}

// ---------- heads at t = 0 ----------
__global__ void k_heads0(const float* __restrict__ sT,
                         const float* __restrict__ Wo1, const float* __restrict__ bo1,
                         const float* __restrict__ Wo2, const float* __restrict__ bo2,
                         float* __restrict__ out) {
  int n = blockIdx.x * blockDim.x + threadIdx.x;
  if (n >= NN) return;
  float p1 = bo1[0], p2 = bo2[0];
  #pragma unroll 8
  for (int c = 0; c < 64; c++) {
    p1 += sT[(long)c * NN + n] * Wo1[c];
    p2 += sT[(long)(64 + c) * NN + n] * Wo2[c];
  }
  out[n] = 1.f / (1.f + expf(-p1));
  out[O2OFF + n] = 1.f / (1.f + expf(-p2));
}

#define PFD 10   /* software-pipeline depth: 2*PFD wave-loads (20KB) in flight */

// ---------- fused ODE eval: k = relu(uT@A^T + bt); RK4 combine; uT_next = Wt^T t_next ----------
__global__ __launch_bounds__(256) void k_feval(
    const f16* __restrict__ A16p, const f16* __restrict__ uin,
    const f16* __restrict__ WtT16, const float* __restrict__ bt,
    const float* __restrict__ vt, int st, int variant,
    float* __restrict__ sT, float* __restrict__ accT,
    f16* __restrict__ uout,
    const float* __restrict__ Wo1, const float* __restrict__ bo1,
    const float* __restrict__ Wo2, const float* __restrict__ bo2,
    float* __restrict__ out) {
  __shared__ __attribute__((aligned(16))) char ulds[32 * 128 * 2];
  __shared__ float hbuf[2][32];

  int tile = blockIdx.x;
  int i0 = tile * 32;
  int tid = threadIdx.x;
  int w = tid >> 6, l = tid & 63, lr = l & 31, lg = l >> 5;

  // ---- main GEMM: D[c][i] = sum_k uT[c][k] * A[i][k], packed streams ----
  // Each wave reads two SEQUENTIAL streams in 1KB bursts; depth-PFD rotating
  // register pipeline keeps ~2*PFD KB/wave in flight (latency-bound fix).
  // a-side (uT): nontemporal; b-side (A16p) is identical across the 4 waves
  // so L1 serves 3/4 of it.
  const f16* ap = uin  + ((long)(w * 500) * 64 + l) * 8;
  const f16* bp = A16p + ((long)(tile * 500) * 64 + l) * 8;
  f32x16 acc0 = {}, acc1 = {}, acc2 = {}, acc3 = {};
  f16x8 Af[PFD], Bf[PFD];
  #pragma unroll
  for (int d = 0; d < PFD; d++) {
    Af[d] = __builtin_nontemporal_load((const f16x8*)(ap + (long)d * 512));
    Bf[d] = *(const f16x8*)(bp + (long)d * 512);
  }
  for (int s0 = 0; s0 + PFD < 500; s0 += PFD) {
    #pragma unroll
    for (int d = 0; d < PFD; d++) {
      f16x8 a = Af[d], b = Bf[d];
      Af[d] = __builtin_nontemporal_load((const f16x8*)(ap + (long)(s0 + PFD + d) * 512));
      Bf[d] = *(const f16x8*)(bp + (long)(s0 + PFD + d) * 512);
      if ((d & 3) == 0)      acc0 = __builtin_amdgcn_mfma_f32_32x32x16_f16(a, b, acc0, 0, 0, 0);
      else if ((d & 3) == 1) acc1 = __builtin_amdgcn_mfma_f32_32x32x16_f16(a, b, acc1, 0, 0, 0);
      else if ((d & 3) == 2) acc2 = __builtin_amdgcn_mfma_f32_32x32x16_f16(a, b, acc2, 0, 0, 0);
      else                   acc3 = __builtin_amdgcn_mfma_f32_32x32x16_f16(a, b, acc3, 0, 0, 0);
    }
  }
  #pragma unroll
  for (int d = 0; d < PFD; d++) {
    if ((d & 3) == 0)      acc0 = __builtin_amdgcn_mfma_f32_32x32x16_f16(Af[d], Bf[d], acc0, 0, 0, 0);
    else if ((d & 3) == 1) acc1 = __builtin_amdgcn_mfma_f32_32x32x16_f16(Af[d], Bf[d], acc1, 0, 0, 0);
    else if ((d & 3) == 2) acc2 = __builtin_amdgcn_mfma_f32_32x32x16_f16(Af[d], Bf[d], acc2, 0, 0, 0);
    else                   acc3 = __builtin_amdgcn_mfma_f32_32x32x16_f16(Af[d], Bf[d], acc3, 0, 0, 0);
  }
  f32x16 acc = (acc0 + acc1) + (acc2 + acc3);

  float dt = vt[st + 1] - vt[st];
  int i = i0 + lr;

  // ---- relu + bias, RK4 combine (elementwise, block-local) ----
  float tn[16];
  #pragma unroll
  for (int r = 0; r < 16; r++) {
    int c = 32 * w + (r & 3) + 8 * (r >> 2) + 4 * lg;
    float kv = acc[r] + bt[c];
    kv = kv > 0.f ? kv : 0.f;
    long g = (long)c * NN + i;
    if (variant == 0) {
      accT[g] = kv;
      tn[r] = sT[g] + 0.5f * dt * kv;
    } else if (variant == 1) {
      accT[g] += 2.f * kv;
      tn[r] = sT[g] + 0.5f * dt * kv;
    } else if (variant == 2) {
      accT[g] += 2.f * kv;
      tn[r] = sT[g] + dt * kv;
    } else {
      float sn = sT[g] + (dt / 6.f) * (accT[g] + kv);
      sT[g] = sn;
      tn[r] = sn;
    }
  }

  // ---- stage t_next (fp16) into LDS [i][m], XOR-swizzled ----
  #pragma unroll
  for (int r = 0; r < 16; r += 2) {
    int c = 32 * w + (r & 3) + 8 * (r >> 2) + 4 * lg;   // r even -> c even, pair contiguous
    f16 pk[2] = { (f16)tn[r], (f16)tn[r + 1] };
    int byte = lr * 256 + ((c * 2) ^ ((lr & 15) << 4));
    *(unsigned int*)(ulds + byte) = *(unsigned int*)pk;
  }
  __syncthreads();

  // ---- uT_next tile = Wt^T @ t_next  (K = 128) ----
  f32x16 uacc = {};
  #pragma unroll
  for (int s = 0; s < 8; s++) {
    int m0 = s * 16 + 8 * lg;
    f16x8 af = *(const f16x8*)(WtT16 + (32 * w + lr) * 128 + m0);
    int byte = lr * 256 + ((m0 * 2) ^ ((lr & 15) << 4));
    f16x8 bf = *(const f16x8*)(ulds + byte);
    uacc = __builtin_amdgcn_mfma_f32_32x32x16_f16(af, bf, uacc, 0, 0, 0);
  }
  // packed write: u_next[c=32w+cc][k=i0+lr]
  #pragma unroll
  for (int r = 0; r < 16; r++) {
    int cc = (r & 3) + 8 * (r >> 2) + 4 * lg;
    int s  = (i0 + lr) >> 4;
    int lp = cc + 32 * ((lr >> 3) & 1);
    int j  = lr & 7;
    uout[((long)(w * 500 + s) * 64 + lp) * 8 + j] = (f16)uacc[r];
  }

  // ---- heads (variant 3 only) ----
  if (variant == 3) {
    if (tid < 64) ((float*)hbuf)[tid] = 0.f;
    __syncthreads();
    float p1 = 0.f, p2 = 0.f;
    #pragma unroll
    for (int r = 0; r < 16; r++) {
      int c = 32 * w + (r & 3) + 8 * (r >> 2) + 4 * lg;
      if (c < 64) p1 += tn[r] * Wo1[c];
      else        p2 += tn[r] * Wo2[c - 64];
    }
    atomicAdd(&hbuf[0][lr], p1);
    atomicAdd(&hbuf[1][lr], p2);
    __syncthreads();
    if (tid < 32) {
      float z = hbuf[0][tid] + bo1[0];
      out[(st + 1) * NN + i0 + tid] = 1.f / (1.f + expf(-z));
    } else if (tid < 64) {
      float z = hbuf[1][tid - 32] + bo2[0];
      out[O2OFF + (st + 1) * NN + i0 + (tid - 32)] = 1.f / (1.f + expf(-z));
    }
  }
}

extern "C" void kernel_launch(void* const* d_in, const int* in_sizes, int n_in,
                              void* d_out, int out_size, void* d_ws, size_t ws_size,
                              hipStream_t stream) {
  const float* vt   = (const float*)d_in[0];
  const float* y1   = (const float*)d_in[1];
  const float* y2   = (const float*)d_in[2];
  const float* A    = (const float*)d_in[3];
  const float* Wi1a = (const float*)d_in[4];
  const float* bi1a = (const float*)d_in[5];
  const float* Wi1b = (const float*)d_in[6];
  const float* bi1b = (const float*)d_in[7];
  const float* Wi2a = (const float*)d_in[8];
  const float* bi2a = (const float*)d_in[9];
  const float* Wi2b = (const float*)d_in[10];
  const float* bi2b = (const float*)d_in[11];
  const float* Wt   = (const float*)d_in[12];
  const float* bt   = (const float*)d_in[13];
  const float* Wo1  = (const float*)d_in[14];
  const float* bo1  = (const float*)d_in[15];
  const float* Wo2  = (const float*)d_in[16];
  const float* bo2  = (const float*)d_in[17];
  float* out = (float*)d_out;

  char* ws = (char*)d_ws;
  f16*   A16p  = (f16*)(ws);                      // 128,000,000 B (fragment-packed)
  f16*   WtT16 = (f16*)(ws + 128000000);          //      32,768 B
  f16*   uA    = (f16*)(ws + 128032768);          //   2,048,000 B (fragment-packed)
  f16*   uB    = (f16*)(ws + 130080768);          //   2,048,000 B (fragment-packed)
  float* sT    = (float*)(ws + 132128768);        //   4,096,000 B
  float* accT  = (float*)(ws + 136224768);        //   4,096,000 B  (total ~140.3 MB)

  k_cvt_a <<<31250, 256, 0, stream>>>(A, A16p);   // 8M threads, one 16B frag each
  k_setup <<<512, 256, 0, stream>>>(Wt, WtT16, y1, y2, out + XOFF);
  k_embed <<<125, 256, 0, stream>>>(y1, y2, Wi1a, bi1a, Wi1b, bi1b,
                                    Wi2a, bi2a, Wi2b, bi2b, sT);
  k_wtmul <<<250, 256, 0, stream>>>(sT, WtT16, uA);
  k_heads0<<<32, 256, 0, stream>>>(sT, Wo1, bo1, Wo2, bo2, out);

  f16* bufs[2] = { uA, uB };
  int pp = 0;
  for (int st = 0; st < 19; st++) {
    for (int v = 0; v < 4; v++) {
      k_feval<<<250, 256, 0, stream>>>(A16p, bufs[pp], WtT16, bt, vt, st, v,
                                       sT, accT, bufs[pp ^ 1],
                                       Wo1, bo1, Wo2, bo2, out);
      pp ^= 1;
    }
  }
}